// Round 19
// baseline (130.457 us; speedup 1.0000x reference)
//
#include <hip/hip_runtime.h>
#include <hip/hip_fp16.h>

typedef _Float16 half8  __attribute__((ext_vector_type(8)));
typedef _Float16 half4  __attribute__((ext_vector_type(4)));
typedef _Float16 h2v    __attribute__((ext_vector_type(2)));
typedef __fp16   fp16x2 __attribute__((ext_vector_type(2)));
typedef float    f32x4  __attribute__((ext_vector_type(4)));

#define B_N   2048
#define KLTOT 2048
#define P_    2052        // xt col stride (dwords)
#define NSKEL 7
#define NCOMP 8
#define WROWM 255         // ws window: 256 rows x 2048 cols x 4B = 2 MB

__device__ __forceinline__ int hmap(int g, int e) {
    return (g < 2) ? ((e < 5) ? g * 5 + e : -1)
                   : ((e < 4) ? 10 + (g - 2) * 4 + e : -1);
}

__device__ __forceinline__ unsigned int f16b(float f) {
    union { _Float16 h; unsigned short u; } c;
    c.h = (_Float16)f;
    return (unsigned int)c.u;
}

// ================= real kernel: R15 EXACT (session best, 27.06) =================
__global__ __launch_bounds__(512, 4) void fused_all(
    const float* __restrict__ x,
    const float* __restrict__ W1, const float* __restrict__ b1,
    const float* __restrict__ W2, const float* __restrict__ b2,
    const float* __restrict__ W3, const float* __restrict__ b3,
    float* __restrict__ out)
{
    __shared__ float        xt[4 * P_];
    __shared__ unsigned int afb[1024];
    __shared__ float        wred[8][4][2];
    __shared__ unsigned int w1h[4][16], b1h[4][16], w3h[4][8];
    __shared__ float        b2f[4][16], smu[4], srs[4], sb3v[4];

    const int tid = threadIdx.x;
    const int bid = blockIdx.x;
    const int xk = bid & 7, jj = bid >> 3;
    const int cols0 = xk * 256 + (jj >> 3) * 32 + (jj & 7) * 4;
    const int w = tid >> 6, l = tid & 63;

    float s[4] = {0.f,0.f,0.f,0.f}, s2[4] = {0.f,0.f,0.f,0.f};
#pragma unroll
    for (int i = 0; i < 4; ++i) {
        int r = i * 512 + tid;
        f32x4 v = *(const f32x4*)(x + (size_t)r * KLTOT + cols0);
#pragma unroll
        for (int e = 0; e < 4; ++e) {
            s[e] += v[e];
            s2[e] = fmaf(v[e], v[e], s2[e]);
            xt[e * P_ + r] = v[e];
        }
    }
    {
        float* W2tmp = (float*)afb;
        if (tid < 216)
            ((float4*)W2tmp)[tid] = ((const float4*)(W2 + (size_t)cols0 * 216))[tid];
    }
    float w1r0 = 0.f, w1r1 = 0.f, b1r0 = 0.f, b1r1 = 0.f;
    if (tid < 64) {
        int c2 = tid >> 4, ll = tid & 15, gg = ll >> 2, q = ll & 3;
        if (q < 3) {
            int h0 = hmap(gg, q * 2), h1_ = hmap(gg, q * 2 + 1);
            if (h0 >= 0) {
                w1r0 = W1[(size_t)(cols0 + c2) * 18 + h0];
                b1r0 = b1[(size_t)(cols0 + c2) * 18 + h0];
            }
            if (h1_ >= 0) {
                w1r1 = W1[(size_t)(cols0 + c2) * 18 + h1_];
                b1r1 = b1[(size_t)(cols0 + c2) * 18 + h1_];
            }
        }
    }
#pragma unroll
    for (int e = 0; e < 4; ++e) {
#pragma unroll
        for (int m = 1; m < 64; m <<= 1) {
            s[e]  += __shfl_xor(s[e],  m, 64);
            s2[e] += __shfl_xor(s2[e], m, 64);
        }
    }
    if (l == 0) {
#pragma unroll
        for (int e = 0; e < 4; ++e) { wred[w][e][0] = s[e]; wred[w][e][1] = s2[e]; }
    }
    __syncthreads();

    if (tid < 4) {
        float S = 0.f, S2 = 0.f;
#pragma unroll
        for (int ww = 0; ww < 8; ++ww) { S += wred[ww][tid][0]; S2 += wred[ww][tid][1]; }
        float mu  = S / (float)B_N;
        float var = fmaxf(S2 / (float)B_N - mu * mu, 0.f);
        smu[tid]  = mu;
        srs[tid]  = 1.f / (sqrtf(var) + 1e-8f);
        sb3v[tid] = b3[cols0 + tid];
    }
    unsigned int dw[2];
    {
        const float* W2tmp = (const float*)afb;
#pragma unroll
        for (int i = 0; i < 2; ++i) {
            int idx = i * 512 + tid;
            int col = idx >> 8, d = idx & 255;
            unsigned int u[2];
#pragma unroll
            for (int h = 0; h < 2; ++h) {
                int id2 = d * 2 + h;
                int gg = id2 >> 7, jq = (id2 >> 3) & 15, e = id2 & 7;
                int hh = hmap(gg, e);
                float v = (hh >= 0 && jq < 12) ? W2tmp[col * 216 + hh * 12 + jq] : 0.f;
                u[h] = f16b(v);
            }
            dw[i] = u[0] | (u[1] << 16);
        }
    }
    if (tid >= 64 && tid < 128) {
        int t2 = tid - 64, c2 = t2 >> 4, ll = t2 & 15;
        b2f[c2][ll] = (ll < 12) ? b2[(size_t)(cols0 + c2) * 12 + ll] : 0.f;
    } else if (tid >= 128 && tid < 160) {
        int t2 = tid - 128, c2 = t2 >> 3, ll = t2 & 7;
        int j0 = 2 * ll, j1 = 2 * ll + 1;
        float v0 = (j0 < 12) ? W3[(size_t)(cols0 + c2) * 12 + j0] : 0.f;
        float v1 = (j1 < 12) ? W3[(size_t)(cols0 + c2) * 12 + j1] : 0.f;
        w3h[c2][ll] = f16b(v0) | (f16b(v1) << 16);
    }
    __syncthreads();

#pragma unroll
    for (int i = 0; i < 2; ++i)
        afb[i * 512 + tid] = dw[i];
    if (tid < 64) {
        int c2 = tid >> 4, ll = tid & 15, q = ll & 3;
        unsigned int wu = 0, bu = 0;
        if (q < 3) {
            float mu = smu[c2], rs = srs[c2];
            float w0 = w1r0 * rs, w1v = w1r1 * rs;
            float b0 = fmaf(-mu, w0, b1r0), b1v = fmaf(-mu, w1v, b1r1);
            wu = f16b(w0) | (f16b(w1v) << 16);
            bu = f16b(b0) | (f16b(b1v) << 16);
        }
        w1h[c2][ll] = wu;
        b1h[c2][ll] = bu;
    }
    __syncthreads();

    const int g = l >> 4, lj = l & 15;
    const int cl = w & 3, rb0 = (w >> 2) * 1024;
    const h2v z2 = {(_Float16)0.f, (_Float16)0.f};
    const f32x4 zc = {0.f, 0.f, 0.f, 0.f};

    union { uint4 u; half8 h; } af;
    af.u = *(const uint4*)&afb[cl * 256 + (g * 16 + lj) * 4];
    union { uint4 u; h2v p[4]; } w1u, b1u;
    w1u.u = *(const uint4*)&w1h[cl][g * 4];
    b1u.u = *(const uint4*)&b1h[cl][g * 4];
    union { uint2 u; half4 h; } a2;
    a2.u = *(const uint2*)&w3h[cl][g * 2];
    f32x4 b2r = *(const f32x4*)&b2f[cl][g * 4];
    float b3v = sb3v[cl];

    float res[16];
    const float* xb = &xt[cl * P_ + rb0 + lj];
#pragma unroll
    for (int m16 = 0; m16 < 4; ++m16) {
#pragma unroll
        for (int mi = 0; mi < 16; ++mi) {
            int rc = m16 * 16 + mi;
            float xsv = xb[rc * 16];
            _Float16 xh = (_Float16)xsv;
            h2v x2 = {xh, xh};
            union { h2v p[4]; half8 h; } bf;
            bf.p[0] = __builtin_elementwise_max(x2 * w1u.p[0] + b1u.p[0], z2);
            bf.p[1] = __builtin_elementwise_max(x2 * w1u.p[1] + b1u.p[1], z2);
            bf.p[2] = __builtin_elementwise_max(x2 * w1u.p[2] + b1u.p[2], z2);
            bf.p[3] = z2;

            f32x4 acc = __builtin_amdgcn_mfma_f32_16x16x32_f16(af.h, bf.h, b2r, 0, 0, 0);

            union { fp16x2 c[2]; half4 h; } zf;
            zf.c[0] = __builtin_amdgcn_cvt_pkrtz(fmaxf(acc[0], 0.f), fmaxf(acc[1], 0.f));
            zf.c[1] = __builtin_amdgcn_cvt_pkrtz(fmaxf(acc[2], 0.f), fmaxf(acc[3], 0.f));

            f32x4 acc2 = __builtin_amdgcn_mfma_f32_16x16x16f16(a2.h, zf.h, zc, 0, 0, 0);

            if (m16 == g) res[mi] = acc2[0] + b3v;
        }
    }
    {
        float* tb = &xt[cl * P_ + rb0 + lj];
#pragma unroll
        for (int mi = 0; mi < 16; ++mi)
            tb[(g * 16 + mi) * 16] = res[mi];
    }
    __syncthreads();

#pragma unroll
    for (int i = 0; i < 4; ++i) {
        int r = i * 512 + tid;
        f32x4 v = { xt[0 * P_ + r], xt[1 * P_ + r], xt[2 * P_ + r], xt[3 * P_ + r] };
        *(f32x4*)(out + (size_t)r * KLTOT + cols0) = v;
    }
}

// ================= diag 1: skeleton (everything EXCEPT Phase C), x NSKEL =================
__global__ __launch_bounds__(512, 4) void diag_skel(
    const float* __restrict__ x,
    const float* __restrict__ W1, const float* __restrict__ b1,
    const float* __restrict__ W2, const float* __restrict__ b2,
    const float* __restrict__ W3, const float* __restrict__ b3,
    float* __restrict__ ws)
{
    __shared__ float        xt[4 * P_];
    __shared__ unsigned int afb[1024];
    __shared__ float        wred[8][4][2];
    __shared__ unsigned int w1h[4][16], b1h[4][16], w3h[4][8];
    __shared__ float        b2f[4][16], smu[4], srs[4], sb3v[4];

    const int tid = threadIdx.x;
    const int bid = blockIdx.x;
    const int xk = bid & 7, jj = bid >> 3;
    const int cols0 = xk * 256 + (jj >> 3) * 32 + (jj & 7) * 4;
    const int w = tid >> 6, l = tid & 63;

#pragma unroll 1
    for (int rep = 0; rep < NSKEL; ++rep) {
        float s[4] = {0.f,0.f,0.f,0.f}, s2[4] = {0.f,0.f,0.f,0.f};
#pragma unroll
        for (int i = 0; i < 4; ++i) {
            int r = i * 512 + tid;
            f32x4 v = *(const f32x4*)(x + (size_t)r * KLTOT + cols0);
#pragma unroll
            for (int e = 0; e < 4; ++e) {
                s[e] += v[e];
                s2[e] = fmaf(v[e], v[e], s2[e]);
                xt[e * P_ + r] = v[e];
            }
        }
        {
            float* W2tmp = (float*)afb;
            if (tid < 216)
                ((float4*)W2tmp)[tid] = ((const float4*)(W2 + (size_t)cols0 * 216))[tid];
        }
        float w1r0 = 0.f, w1r1 = 0.f, b1r0 = 0.f, b1r1 = 0.f;
        if (tid < 64) {
            int c2 = tid >> 4, ll = tid & 15, gg = ll >> 2, q = ll & 3;
            if (q < 3) {
                int h0 = hmap(gg, q * 2), h1_ = hmap(gg, q * 2 + 1);
                if (h0 >= 0) {
                    w1r0 = W1[(size_t)(cols0 + c2) * 18 + h0];
                    b1r0 = b1[(size_t)(cols0 + c2) * 18 + h0];
                }
                if (h1_ >= 0) {
                    w1r1 = W1[(size_t)(cols0 + c2) * 18 + h1_];
                    b1r1 = b1[(size_t)(cols0 + c2) * 18 + h1_];
                }
            }
        }
#pragma unroll
        for (int e = 0; e < 4; ++e) {
#pragma unroll
            for (int m = 1; m < 64; m <<= 1) {
                s[e]  += __shfl_xor(s[e],  m, 64);
                s2[e] += __shfl_xor(s2[e], m, 64);
            }
        }
        if (l == 0) {
#pragma unroll
            for (int e = 0; e < 4; ++e) { wred[w][e][0] = s[e]; wred[w][e][1] = s2[e]; }
        }
        __syncthreads();

        if (tid < 4) {
            float S = 0.f, S2 = 0.f;
#pragma unroll
            for (int ww = 0; ww < 8; ++ww) { S += wred[ww][tid][0]; S2 += wred[ww][tid][1]; }
            float mu  = S / (float)B_N;
            float var = fmaxf(S2 / (float)B_N - mu * mu, 0.f);
            smu[tid]  = mu;
            srs[tid]  = 1.f / (sqrtf(var) + 1e-8f);
            sb3v[tid] = b3[cols0 + tid];
        }
        unsigned int dw[2];
        {
            const float* W2tmp = (const float*)afb;
#pragma unroll
            for (int i = 0; i < 2; ++i) {
                int idx = i * 512 + tid;
                int col = idx >> 8, d = idx & 255;
                unsigned int u[2];
#pragma unroll
                for (int h = 0; h < 2; ++h) {
                    int id2 = d * 2 + h;
                    int gg = id2 >> 7, jq = (id2 >> 3) & 15, e = id2 & 7;
                    int hh = hmap(gg, e);
                    float v = (hh >= 0 && jq < 12) ? W2tmp[col * 216 + hh * 12 + jq] : 0.f;
                    u[h] = f16b(v);
                }
                dw[i] = u[0] | (u[1] << 16);
            }
        }
        if (tid >= 64 && tid < 128) {
            int t2 = tid - 64, c2 = t2 >> 4, ll = t2 & 15;
            b2f[c2][ll] = (ll < 12) ? b2[(size_t)(cols0 + c2) * 12 + ll] : 0.f;
        } else if (tid >= 128 && tid < 160) {
            int t2 = tid - 128, c2 = t2 >> 3, ll = t2 & 7;
            int j0 = 2 * ll, j1 = 2 * ll + 1;
            float v0 = (j0 < 12) ? W3[(size_t)(cols0 + c2) * 12 + j0] : 0.f;
            float v1 = (j1 < 12) ? W3[(size_t)(cols0 + c2) * 12 + j1] : 0.f;
            w3h[c2][ll] = f16b(v0) | (f16b(v1) << 16);
        }
        __syncthreads();

#pragma unroll
        for (int i = 0; i < 2; ++i)
            afb[i * 512 + tid] = dw[i];
        if (tid < 64) {
            int c2 = tid >> 4, ll = tid & 15, q = ll & 3;
            unsigned int wu = 0, bu = 0;
            if (q < 3) {
                float mu = smu[c2], rs = srs[c2];
                float w0 = w1r0 * rs, w1v = w1r1 * rs;
                float b0 = fmaf(-mu, w0, b1r0), b1v = fmaf(-mu, w1v, b1r1);
                wu = f16b(w0) | (f16b(w1v) << 16);
                bu = f16b(b0) | (f16b(b1v) << 16);
            }
            w1h[c2][ll] = wu;
            b1h[c2][ll] = bu;
        }
        __syncthreads();

        // store xt -> ws (2 MB window, same 16B-granule pattern as real store)
#pragma unroll
        for (int i = 0; i < 4; ++i) {
            int r = i * 512 + tid;
            f32x4 v = { xt[0 * P_ + r], xt[1 * P_ + r], xt[2 * P_ + r], xt[3 * P_ + r] };
            *(f32x4*)(ws + (size_t)(r & WROWM) * KLTOT + cols0) = v;
        }
        __syncthreads();
    }
}

// ================= diag 2: Phase C only, x NCOMP (no x traffic) =================
__global__ __launch_bounds__(512, 4) void diag_comp(
    const float* __restrict__ W1, const float* __restrict__ b1,
    const float* __restrict__ W2, const float* __restrict__ b2,
    const float* __restrict__ W3, const float* __restrict__ b3,
    float* __restrict__ ws)
{
    __shared__ float        xt[4 * P_];
    __shared__ unsigned int afb[1024];
    __shared__ unsigned int w1h[4][16], b1h[4][16], w3h[4][8];
    __shared__ float        b2f[4][16], sb3v[4];

    const int tid = threadIdx.x;
    const int bid = blockIdx.x;
    const int xk = bid & 7, jj = bid >> 3;
    const int cols0 = xk * 256 + (jj >> 3) * 32 + (jj & 7) * 4;
    const int w = tid >> 6, l = tid & 63;

    // zero-fill xt (deterministic Phase C input)
    for (int i = tid; i < 4 * P_; i += 512)
        xt[i] = 0.f;
    {
        float* W2tmp = (float*)afb;
        if (tid < 216)
            ((float4*)W2tmp)[tid] = ((const float4*)(W2 + (size_t)cols0 * 216))[tid];
    }
    float w1r0 = 0.f, w1r1 = 0.f, b1r0 = 0.f, b1r1 = 0.f;
    if (tid < 64) {
        int c2 = tid >> 4, ll = tid & 15, gg = ll >> 2, q = ll & 3;
        if (q < 3) {
            int h0 = hmap(gg, q * 2), h1_ = hmap(gg, q * 2 + 1);
            if (h0 >= 0) {
                w1r0 = W1[(size_t)(cols0 + c2) * 18 + h0];
                b1r0 = b1[(size_t)(cols0 + c2) * 18 + h0];
            }
            if (h1_ >= 0) {
                w1r1 = W1[(size_t)(cols0 + c2) * 18 + h1_];
                b1r1 = b1[(size_t)(cols0 + c2) * 18 + h1_];
            }
        }
    }
    if (tid < 4) sb3v[tid] = b3[cols0 + tid];
    __syncthreads();

    unsigned int dw[2];
    {
        const float* W2tmp = (const float*)afb;
#pragma unroll
        for (int i = 0; i < 2; ++i) {
            int idx = i * 512 + tid;
            int col = idx >> 8, d = idx & 255;
            unsigned int u[2];
#pragma unroll
            for (int h = 0; h < 2; ++h) {
                int id2 = d * 2 + h;
                int gg = id2 >> 7, jq = (id2 >> 3) & 15, e = id2 & 7;
                int hh = hmap(gg, e);
                float v = (hh >= 0 && jq < 12) ? W2tmp[col * 216 + hh * 12 + jq] : 0.f;
                u[h] = f16b(v);
            }
            dw[i] = u[0] | (u[1] << 16);
        }
    }
    if (tid >= 64 && tid < 128) {
        int t2 = tid - 64, c2 = t2 >> 4, ll = t2 & 15;
        b2f[c2][ll] = (ll < 12) ? b2[(size_t)(cols0 + c2) * 12 + ll] : 0.f;
    } else if (tid >= 128 && tid < 160) {
        int t2 = tid - 128, c2 = t2 >> 3, ll = t2 & 7;
        int j0 = 2 * ll, j1 = 2 * ll + 1;
        float v0 = (j0 < 12) ? W3[(size_t)(cols0 + c2) * 12 + j0] : 0.f;
        float v1 = (j1 < 12) ? W3[(size_t)(cols0 + c2) * 12 + j1] : 0.f;
        w3h[c2][ll] = f16b(v0) | (f16b(v1) << 16);
    }
    __syncthreads();
#pragma unroll
    for (int i = 0; i < 2; ++i)
        afb[i * 512 + tid] = dw[i];
    if (tid < 64) {
        // mu=0, rs=1 fold (deterministic stand-in)
        int c2 = tid >> 4, ll = tid & 15, q = ll & 3;
        unsigned int wu = 0, bu = 0;
        if (q < 3) {
            wu = f16b(w1r0) | (f16b(w1r1) << 16);
            bu = f16b(b1r0) | (f16b(b1r1) << 16);
        }
        w1h[c2][ll] = wu;
        b1h[c2][ll] = bu;
    }
    __syncthreads();

    const int g = l >> 4, lj = l & 15;
    const int cl = w & 3, rb0 = (w >> 2) * 1024;
    const h2v z2 = {(_Float16)0.f, (_Float16)0.f};
    const f32x4 zc = {0.f, 0.f, 0.f, 0.f};

    union { uint4 u; half8 h; } af;
    af.u = *(const uint4*)&afb[cl * 256 + (g * 16 + lj) * 4];
    union { uint4 u; h2v p[4]; } w1u, b1u;
    w1u.u = *(const uint4*)&w1h[cl][g * 4];
    b1u.u = *(const uint4*)&b1h[cl][g * 4];
    union { uint2 u; half4 h; } a2;
    a2.u = *(const uint2*)&w3h[cl][g * 2];
    f32x4 b2r = *(const f32x4*)&b2f[cl][g * 4];
    float b3v = sb3v[cl];

#pragma unroll 1
    for (int rep = 0; rep < NCOMP; ++rep) {
        float res[16];
        const float* xb = &xt[cl * P_ + rb0 + lj];
#pragma unroll
        for (int m16 = 0; m16 < 4; ++m16) {
#pragma unroll
            for (int mi = 0; mi < 16; ++mi) {
                int rc = m16 * 16 + mi;
                float xsv = xb[rc * 16];
                _Float16 xh = (_Float16)xsv;
                h2v x2 = {xh, xh};
                union { h2v p[4]; half8 h; } bf;
                bf.p[0] = __builtin_elementwise_max(x2 * w1u.p[0] + b1u.p[0], z2);
                bf.p[1] = __builtin_elementwise_max(x2 * w1u.p[1] + b1u.p[1], z2);
                bf.p[2] = __builtin_elementwise_max(x2 * w1u.p[2] + b1u.p[2], z2);
                bf.p[3] = z2;

                f32x4 acc = __builtin_amdgcn_mfma_f32_16x16x32_f16(af.h, bf.h, b2r, 0, 0, 0);

                union { fp16x2 c[2]; half4 h; } zf;
                zf.c[0] = __builtin_amdgcn_cvt_pkrtz(fmaxf(acc[0], 0.f), fmaxf(acc[1], 0.f));
                zf.c[1] = __builtin_amdgcn_cvt_pkrtz(fmaxf(acc[2], 0.f), fmaxf(acc[3], 0.f));

                f32x4 acc2 = __builtin_amdgcn_mfma_f32_16x16x16f16(a2.h, zf.h, zc, 0, 0, 0);

                if (m16 == g) res[mi] = acc2[0] + b3v;
            }
        }
        float* tb = &xt[cl * P_ + rb0 + lj];
#pragma unroll
        for (int mi = 0; mi < 16; ++mi)
            tb[(g * 16 + mi) * 16] = res[mi];
        __syncthreads();
    }

    // final store keeps everything live (2 MB ws window)
#pragma unroll
    for (int i = 0; i < 4; ++i) {
        int r = i * 512 + tid;
        f32x4 v = { xt[0 * P_ + r], xt[1 * P_ + r], xt[2 * P_ + r], xt[3 * P_ + r] };
        *(f32x4*)(ws + (size_t)(r & WROWM) * KLTOT + cols0) = v;
    }
}

extern "C" void kernel_launch(void* const* d_in, const int* in_sizes, int n_in,
                              void* d_out, int out_size, void* d_ws, size_t ws_size,
                              hipStream_t stream) {
    const float* x  = (const float*)d_in[0];
    const float* W1 = (const float*)d_in[1];
    const float* b1 = (const float*)d_in[2];
    const float* W2 = (const float*)d_in[3];
    const float* b2 = (const float*)d_in[4];
    const float* W3 = (const float*)d_in[5];
    const float* b3 = (const float*)d_in[6];
    float* out = (float*)d_out;
    float* ws  = (float*)d_ws;

    fused_all<<<dim3(512), 512, 0, stream>>>(x, W1, b1, W2, b2, W3, b3, out);
    diag_skel<<<dim3(512), 512, 0, stream>>>(x, W1, b1, W2, b2, W3, b3, ws);
    diag_comp<<<dim3(512), 512, 0, stream>>>(W1, b1, W2, b2, W3, b3, ws);
}

// Round 21
// 28.617 us; speedup vs baseline: 4.5587x; 4.5587x over previous
//
#include <hip/hip_runtime.h>
#include <hip/hip_fp16.h>

typedef _Float16 half8  __attribute__((ext_vector_type(8)));
typedef _Float16 half4  __attribute__((ext_vector_type(4)));
typedef __fp16   fp16x2 __attribute__((ext_vector_type(2)));
typedef float    f32x4  __attribute__((ext_vector_type(4)));

#define B_N   2048
#define KLTOT 2048
#define P_    2052        // xt col stride (dwords): %32==4 (2-way banks), %4==0 (16B align)

// 5/5/4/4 h-slot packing
__device__ __forceinline__ int hmap(int g, int e) {
    return (g < 2) ? ((e < 5) ? g * 5 + e : -1)
                   : ((e < 4) ? 10 + (g - 2) * 4 + e : -1);
}

__device__ __forceinline__ unsigned int f16b(float f) {
    union { _Float16 h; unsigned short u; } c;
    c.h = (_Float16)f;
    return (unsigned int)c.u;
}

// Single kernel. Block = 4 FULL columns x 2048 batches (block-local stats).
// 512 blocks x 512 thr -> 2 blocks/CU, all co-resident.
// R21: h1-build moved to plain f32 VALU (5 fma + 5 max + 3 pkrtz) — no f16-vector
// scalarization, no inline asm. Everything else identical to R15 (27.06 baseline).
__global__ __launch_bounds__(512, 4) void fused_all(
    const float* __restrict__ x,
    const float* __restrict__ W1, const float* __restrict__ b1,
    const float* __restrict__ W2, const float* __restrict__ b2,
    const float* __restrict__ W3, const float* __restrict__ b3,
    float* __restrict__ out)
{
    __shared__ float        xt[4 * P_];          // 32.8 KB  [col][row]
    __shared__ unsigned int afb[1024];           // 4 KB     W2tmp (864 f32) then A-frags
    __shared__ float        wred[8][4][2];
    __shared__ float        w1f[4][32], b1f[4][32];   // f32, slot layout g*8+e
    __shared__ unsigned int w3h[4][8];
    __shared__ float        b2f[4][16], smu[4], srs[4], sb3v[4];

    const int tid = threadIdx.x;
    const int bid = blockIdx.x;
    // XCD-chunked col swizzle: XCD k owns a contiguous 256-col band (2MB < 4MB L2)
    const int xk = bid & 7, jj = bid >> 3;
    const int cols0 = xk * 256 + (jj >> 3) * 32 + (jj & 7) * 4;

    const int w = tid >> 6, l = tid & 63;

    // ---- S1: single x pass: 16B row-slices -> LDS + in-register stats ----
    float s[4] = {0.f,0.f,0.f,0.f}, s2[4] = {0.f,0.f,0.f,0.f};
#pragma unroll
    for (int i = 0; i < 4; ++i) {
        int r = i * 512 + tid;
        f32x4 v = *(const f32x4*)(x + (size_t)r * KLTOT + cols0);
#pragma unroll
        for (int e = 0; e < 4; ++e) {
            s[e] += v[e];
            s2[e] = fmaf(v[e], v[e], s2[e]);
            xt[e * P_ + r] = v[e];
        }
    }
    {   // stage W2 (4 cols x 216 = 864 f32) into afb region
        float* W2tmp = (float*)afb;
        if (tid < 216)
            ((float4*)W2tmp)[tid] = ((const float4*)(W2 + (size_t)cols0 * 216))[tid];
    }
    // prefetch raw W1/b1: one slot per thread (tid<128: c2=tid>>5, slot=tid&31)
    float w1r = 0.f, b1r = 0.f;
    if (tid < 128) {
        int c2 = tid >> 5, t = tid & 31, gg = t >> 3, e = t & 7;
        int h = hmap(gg, e);
        if (h >= 0) {
            w1r = W1[(size_t)(cols0 + c2) * 18 + h];
            b1r = b1[(size_t)(cols0 + c2) * 18 + h];
        }
    }
    // wave-level stats reduce
#pragma unroll
    for (int e = 0; e < 4; ++e) {
#pragma unroll
        for (int m = 1; m < 64; m <<= 1) {
            s[e]  += __shfl_xor(s[e],  m, 64);
            s2[e] += __shfl_xor(s2[e], m, 64);
        }
    }
    if (l == 0) {
#pragma unroll
        for (int e = 0; e < 4; ++e) { wred[w][e][0] = s[e]; wred[w][e][1] = s2[e]; }
    }
    __syncthreads();

    // ---- S2: stats final (t<4) || W2 frag-pack -> regs || mu-free tables ----
    if (tid < 4) {
        float S = 0.f, S2 = 0.f;
#pragma unroll
        for (int ww = 0; ww < 8; ++ww) { S += wred[ww][tid][0]; S2 += wred[ww][tid][1]; }
        float mu  = S / (float)B_N;
        float var = fmaxf(S2 / (float)B_N - mu * mu, 0.f);
        smu[tid]  = mu;
        srs[tid]  = 1.f / (sqrtf(var) + 1e-8f);
        sb3v[tid] = b3[cols0 + tid];
    }
    unsigned int dw[2];
    {
        const float* W2tmp = (const float*)afb;
#pragma unroll
        for (int i = 0; i < 2; ++i) {
            int idx = i * 512 + tid;
            int col = idx >> 8, d = idx & 255;
            unsigned int u[2];
#pragma unroll
            for (int h = 0; h < 2; ++h) {
                int id2 = d * 2 + h;
                int gg = id2 >> 7, jq = (id2 >> 3) & 15, e = id2 & 7;
                int hh = hmap(gg, e);
                float v = (hh >= 0 && jq < 12) ? W2tmp[col * 216 + hh * 12 + jq] : 0.f;
                u[h] = f16b(v);
            }
            dw[i] = u[0] | (u[1] << 16);
        }
    }
    if (tid >= 64 && tid < 128) {
        int t2 = tid - 64, c2 = t2 >> 4, ll = t2 & 15;
        b2f[c2][ll] = (ll < 12) ? b2[(size_t)(cols0 + c2) * 12 + ll] : 0.f;
    } else if (tid >= 128 && tid < 160) {
        int t2 = tid - 128, c2 = t2 >> 3, ll = t2 & 7;
        int j0 = 2 * ll, j1 = 2 * ll + 1;
        float v0 = (j0 < 12) ? W3[(size_t)(cols0 + c2) * 12 + j0] : 0.f;
        float v1 = (j1 < 12) ? W3[(size_t)(cols0 + c2) * 12 + j1] : 0.f;
        w3h[c2][ll] = f16b(v0) | (f16b(v1) << 16);
    }
    __syncthreads();

    // ---- S3: write A-frags || fold W1/b1 with stats (f32 tables) ----
#pragma unroll
    for (int i = 0; i < 2; ++i)
        afb[i * 512 + tid] = dw[i];
    if (tid < 128) {
        int c2 = tid >> 5, t = tid & 31;
        float mu = smu[c2], rs = srs[c2];
        float wv = w1r * rs;
        w1f[c2][t] = wv;
        b1f[c2][t] = fmaf(-mu, wv, b1r);     // (0 for padded slots: w1r=b1r=0)
    }
    __syncthreads();

    // ---- Phase C: dual chained MFMA; wave = 1 col x 1024 rows (64 iters) ----
    const int g = l >> 4, lj = l & 15;
    const int cl = w & 3, rb0 = (w >> 2) * 1024;
    const f32x4 zc = {0.f, 0.f, 0.f, 0.f};

    union { uint4 u; half8 h; } af;
    af.u = *(const uint4*)&afb[cl * 256 + (g * 16 + lj) * 4];
    f32x4 w14 = *(const f32x4*)&w1f[cl][g * 8];
    float w15  = w1f[cl][g * 8 + 4];
    f32x4 b14 = *(const f32x4*)&b1f[cl][g * 8];
    float b15  = b1f[cl][g * 8 + 4];
    union { uint2 u; half4 h; } a2;
    a2.u = *(const uint2*)&w3h[cl][g * 2];
    f32x4 b2r = *(const f32x4*)&b2f[cl][g * 4];
    float b3v = sb3v[cl];

    float res[16];
    const float* xb = &xt[cl * P_ + rb0 + lj];
#pragma unroll
    for (int m16 = 0; m16 < 4; ++m16) {
#pragma unroll
        for (int mi = 0; mi < 16; ++mi) {
            int rc = m16 * 16 + mi;
            float xsv = xb[rc * 16];              // 16-bank broadcast, conflict-free

            // h1 in f32: 5 fma + 5 max + 3 pkrtz (guaranteed full-rate VALU)
            float h0 = fmaxf(fmaf(xsv, w14[0], b14[0]), 0.f);
            float h1 = fmaxf(fmaf(xsv, w14[1], b14[1]), 0.f);
            float h2 = fmaxf(fmaf(xsv, w14[2], b14[2]), 0.f);
            float h3 = fmaxf(fmaf(xsv, w14[3], b14[3]), 0.f);
            float h4 = fmaxf(fmaf(xsv, w15,    b15),    0.f);

            union { fp16x2 c[4]; uint4 u; half8 h; } bf;
            bf.c[0] = __builtin_amdgcn_cvt_pkrtz(h0, h1);
            bf.c[1] = __builtin_amdgcn_cvt_pkrtz(h2, h3);
            bf.c[2] = __builtin_amdgcn_cvt_pkrtz(h4, 0.f);
            bf.u.w  = 0u;

            // MFMA1: Z[j x b16] = W2^T * H1 + b2
            f32x4 acc = __builtin_amdgcn_mfma_f32_16x16x32_f16(af.h, bf.h, b2r, 0, 0, 0);

            union { fp16x2 c[2]; half4 h; } zf;
            zf.c[0] = __builtin_amdgcn_cvt_pkrtz(fmaxf(acc[0], 0.f), fmaxf(acc[1], 0.f));
            zf.c[1] = __builtin_amdgcn_cvt_pkrtz(fmaxf(acc[2], 0.f), fmaxf(acc[3], 0.f));

            // MFMA2: out[b] = W3^T * relu(Z) (j-reduction on matrix pipe)
            f32x4 acc2 = __builtin_amdgcn_mfma_f32_16x16x16f16(a2.h, zf.h, zc, 0, 0, 0);

            if (m16 == g) res[mi] = acc2[0] + b3v;     // rows rb0 + (g*16+mi)*16 + lj
        }
    }
    // overwrite dead x slots (wave-private row range of its own column)
    {
        float* tb = &xt[cl * P_ + rb0 + lj];
#pragma unroll
        for (int mi = 0; mi < 16; ++mi)
            tb[(g * 16 + mi) * 16] = res[mi];
    }
    __syncthreads();

    // ---- store: out[r][cols0..cols0+3] = 16B row-slices (L2-merged) ----
#pragma unroll
    for (int i = 0; i < 4; ++i) {
        int r = i * 512 + tid;
        f32x4 v = { xt[0 * P_ + r], xt[1 * P_ + r], xt[2 * P_ + r], xt[3 * P_ + r] };
        *(f32x4*)(out + (size_t)r * KLTOT + cols0) = v;
    }
}

extern "C" void kernel_launch(void* const* d_in, const int* in_sizes, int n_in,
                              void* d_out, int out_size, void* d_ws, size_t ws_size,
                              hipStream_t stream) {
    const float* x  = (const float*)d_in[0];
    const float* W1 = (const float*)d_in[1];
    const float* b1 = (const float*)d_in[2];
    const float* W2 = (const float*)d_in[3];
    const float* b2 = (const float*)d_in[4];
    const float* W3 = (const float*)d_in[5];
    const float* b3 = (const float*)d_in[6];
    float* out = (float*)d_out;

    fused_all<<<dim3(512), 512, 0, stream>>>(x, W1, b1, W2, b2, W3, b3, out);
}

// Round 22
// 27.108 us; speedup vs baseline: 4.8125x; 1.0557x over previous
//
#include <hip/hip_runtime.h>
#include <hip/hip_fp16.h>

typedef _Float16 half8  __attribute__((ext_vector_type(8)));
typedef _Float16 half4  __attribute__((ext_vector_type(4)));
typedef _Float16 h2v    __attribute__((ext_vector_type(2)));
typedef __fp16   fp16x2 __attribute__((ext_vector_type(2)));
typedef float    f32x4  __attribute__((ext_vector_type(4)));

#define B_N   2048
#define KLTOT 2048
#define P_    2052        // xt col stride (dwords): %32==4 (2-way banks), %4==0 (16B align)

// 5/5/4/4 h-slot packing
__device__ __forceinline__ int hmap(int g, int e) {
    return (g < 2) ? ((e < 5) ? g * 5 + e : -1)
                   : ((e < 4) ? 10 + (g - 2) * 4 + e : -1);
}

__device__ __forceinline__ unsigned int f16b(float f) {
    union { _Float16 h; unsigned short u; } c;
    c.h = (_Float16)f;
    return (unsigned int)c.u;
}

// Single kernel. Block = 4 FULL columns x 2048 batches (block-local stats).
// 512 blocks x 512 thr -> 2 blocks/CU, all co-resident.
// R22 = R15 with zero-overhead Phase-C epilogue: b3 folded into MFMA2's C,
// result stored directly to the just-consumed LDS slot (no res[] array, no
// predication, no final writeback loop).
__global__ __launch_bounds__(512, 4) void fused_all(
    const float* __restrict__ x,
    const float* __restrict__ W1, const float* __restrict__ b1,
    const float* __restrict__ W2, const float* __restrict__ b2,
    const float* __restrict__ W3, const float* __restrict__ b3,
    float* __restrict__ out)
{
    __shared__ float        xt[4 * P_];          // 32.8 KB  [col][row]
    __shared__ unsigned int afb[1024];           // 4 KB     W2tmp (864 f32) then A-frags
    __shared__ float        wred[8][4][2];
    __shared__ unsigned int w1h[4][16], b1h[4][16], w3h[4][8];
    __shared__ float        b2f[4][16], smu[4], srs[4], sb3v[4];

    const int tid = threadIdx.x;
    const int bid = blockIdx.x;
    const int xk = bid & 7, jj = bid >> 3;
    const int cols0 = xk * 256 + (jj >> 3) * 32 + (jj & 7) * 4;

    const int w = tid >> 6, l = tid & 63;

    // ---- S1: single x pass: 16B row-slices -> LDS + in-register stats ----
    float s[4] = {0.f,0.f,0.f,0.f}, s2[4] = {0.f,0.f,0.f,0.f};
#pragma unroll
    for (int i = 0; i < 4; ++i) {
        int r = i * 512 + tid;
        f32x4 v = *(const f32x4*)(x + (size_t)r * KLTOT + cols0);
#pragma unroll
        for (int e = 0; e < 4; ++e) {
            s[e] += v[e];
            s2[e] = fmaf(v[e], v[e], s2[e]);
            xt[e * P_ + r] = v[e];
        }
    }
    {   // stage W2 (4 cols x 216 = 864 f32) into afb region
        float* W2tmp = (float*)afb;
        if (tid < 216)
            ((float4*)W2tmp)[tid] = ((const float4*)(W2 + (size_t)cols0 * 216))[tid];
    }
    // prefetch raw W1/b1 (folded after stats)
    float w1r0 = 0.f, w1r1 = 0.f, b1r0 = 0.f, b1r1 = 0.f;
    if (tid < 64) {
        int c2 = tid >> 4, ll = tid & 15, gg = ll >> 2, q = ll & 3;
        if (q < 3) {
            int h0 = hmap(gg, q * 2), h1_ = hmap(gg, q * 2 + 1);
            if (h0 >= 0) {
                w1r0 = W1[(size_t)(cols0 + c2) * 18 + h0];
                b1r0 = b1[(size_t)(cols0 + c2) * 18 + h0];
            }
            if (h1_ >= 0) {
                w1r1 = W1[(size_t)(cols0 + c2) * 18 + h1_];
                b1r1 = b1[(size_t)(cols0 + c2) * 18 + h1_];
            }
        }
    }
    // wave-level stats reduce
#pragma unroll
    for (int e = 0; e < 4; ++e) {
#pragma unroll
        for (int m = 1; m < 64; m <<= 1) {
            s[e]  += __shfl_xor(s[e],  m, 64);
            s2[e] += __shfl_xor(s2[e], m, 64);
        }
    }
    if (l == 0) {
#pragma unroll
        for (int e = 0; e < 4; ++e) { wred[w][e][0] = s[e]; wred[w][e][1] = s2[e]; }
    }
    __syncthreads();

    // ---- S2: stats final (t<4) || W2 frag-pack -> regs || mu-free tables ----
    if (tid < 4) {
        float S = 0.f, S2 = 0.f;
#pragma unroll
        for (int ww = 0; ww < 8; ++ww) { S += wred[ww][tid][0]; S2 += wred[ww][tid][1]; }
        float mu  = S / (float)B_N;
        float var = fmaxf(S2 / (float)B_N - mu * mu, 0.f);
        smu[tid]  = mu;
        srs[tid]  = 1.f / (sqrtf(var) + 1e-8f);
        sb3v[tid] = b3[cols0 + tid];
    }
    unsigned int dw[2];
    {
        const float* W2tmp = (const float*)afb;
#pragma unroll
        for (int i = 0; i < 2; ++i) {
            int idx = i * 512 + tid;
            int col = idx >> 8, d = idx & 255;
            unsigned int u[2];
#pragma unroll
            for (int h = 0; h < 2; ++h) {
                int id2 = d * 2 + h;
                int gg = id2 >> 7, jq = (id2 >> 3) & 15, e = id2 & 7;
                int hh = hmap(gg, e);
                float v = (hh >= 0 && jq < 12) ? W2tmp[col * 216 + hh * 12 + jq] : 0.f;
                u[h] = f16b(v);
            }
            dw[i] = u[0] | (u[1] << 16);
        }
    }
    if (tid >= 64 && tid < 128) {
        int t2 = tid - 64, c2 = t2 >> 4, ll = t2 & 15;
        b2f[c2][ll] = (ll < 12) ? b2[(size_t)(cols0 + c2) * 12 + ll] : 0.f;
    } else if (tid >= 128 && tid < 160) {
        int t2 = tid - 128, c2 = t2 >> 3, ll = t2 & 7;
        int j0 = 2 * ll, j1 = 2 * ll + 1;
        float v0 = (j0 < 12) ? W3[(size_t)(cols0 + c2) * 12 + j0] : 0.f;
        float v1 = (j1 < 12) ? W3[(size_t)(cols0 + c2) * 12 + j1] : 0.f;
        w3h[c2][ll] = f16b(v0) | (f16b(v1) << 16);
    }
    __syncthreads();

    // ---- S3: write A-frags || fold W1/b1 with stats ----
#pragma unroll
    for (int i = 0; i < 2; ++i)
        afb[i * 512 + tid] = dw[i];
    if (tid < 64) {
        int c2 = tid >> 4, ll = tid & 15, q = ll & 3;
        unsigned int wu = 0, bu = 0;
        if (q < 3) {
            float mu = smu[c2], rs = srs[c2];
            float w0 = w1r0 * rs, w1v = w1r1 * rs;
            float b0 = fmaf(-mu, w0, b1r0), b1v = fmaf(-mu, w1v, b1r1);
            wu = f16b(w0) | (f16b(w1v) << 16);
            bu = f16b(b0) | (f16b(b1v) << 16);
        }
        w1h[c2][ll] = wu;
        b1h[c2][ll] = bu;
    }
    __syncthreads();

    // ---- Phase C: dual chained MFMA; wave = 1 col x 1024 rows (64 iters) ----
    const int g = l >> 4, lj = l & 15;
    const int cl = w & 3, rb0 = (w >> 2) * 1024;

    union { uint4 u; half8 h; } af;
    af.u = *(const uint4*)&afb[cl * 256 + (g * 16 + lj) * 4];
    union { uint4 u; h2v p[4]; } w1u, b1u;
    w1u.u = *(const uint4*)&w1h[cl][g * 4];
    b1u.u = *(const uint4*)&b1h[cl][g * 4];
    union { uint2 u; half4 h; } a2;
    a2.u = *(const uint2*)&w3h[cl][g * 2];
    f32x4 b2r = *(const f32x4*)&b2f[cl][g * 4];
    const float b3v = sb3v[cl];
    const f32x4 bc3 = { b3v, b3v, b3v, b3v };     // b3 folded into MFMA2 C-operand
    const h2v z2 = {(_Float16)0.f, (_Float16)0.f};

    float* xbw = &xt[cl * P_ + rb0 + lj];
    union { h2v p[4]; half8 h; uint4 u; } bf;
    bf.u.w = 0u;                                   // zeroed once

#pragma unroll 16
    for (int rc = 0; rc < 64; ++rc) {
        float xsv = xbw[rc * 16];                  // 16-bank broadcast, conflict-free
        _Float16 xh = (_Float16)xsv;
        h2v x2 = {xh, xh};
        bf.p[0] = __builtin_elementwise_max(x2 * w1u.p[0] + b1u.p[0], z2);
        bf.p[1] = __builtin_elementwise_max(x2 * w1u.p[1] + b1u.p[1], z2);
        bf.p[2] = __builtin_elementwise_max(x2 * w1u.p[2] + b1u.p[2], z2);

        // MFMA1: Z[j x b16] = W2^T * H1 + b2
        f32x4 acc = __builtin_amdgcn_mfma_f32_16x16x32_f16(af.h, bf.h, b2r, 0, 0, 0);

        union { fp16x2 c[2]; half4 h; } zf;
        zf.c[0] = __builtin_amdgcn_cvt_pkrtz(fmaxf(acc[0], 0.f), fmaxf(acc[1], 0.f));
        zf.c[1] = __builtin_amdgcn_cvt_pkrtz(fmaxf(acc[2], 0.f), fmaxf(acc[3], 0.f));

        // MFMA2: out[b] = W3^T * relu(Z) + b3   (C-in = b3 broadcast)
        f32x4 acc2 = __builtin_amdgcn_mfma_f32_16x16x16f16(a2.h, zf.h, bc3, 0, 0, 0);

        // all 4 g-copies identical -> unpredicated store over the consumed x slot
        xbw[rc * 16] = acc2[0];
    }
    __syncthreads();

    // ---- store: out[r][cols0..cols0+3] = 16B row-slices (L2-merged) ----
#pragma unroll
    for (int i = 0; i < 4; ++i) {
        int r = i * 512 + tid;
        f32x4 v = { xt[0 * P_ + r], xt[1 * P_ + r], xt[2 * P_ + r], xt[3 * P_ + r] };
        *(f32x4*)(out + (size_t)r * KLTOT + cols0) = v;
    }
}

extern "C" void kernel_launch(void* const* d_in, const int* in_sizes, int n_in,
                              void* d_out, int out_size, void* d_ws, size_t ws_size,
                              hipStream_t stream) {
    const float* x  = (const float*)d_in[0];
    const float* W1 = (const float*)d_in[1];
    const float* b1 = (const float*)d_in[2];
    const float* W2 = (const float*)d_in[3];
    const float* b2 = (const float*)d_in[4];
    const float* W3 = (const float*)d_in[5];
    const float* b3 = (const float*)d_in[6];
    float* out = (float*)d_out;

    fused_all<<<dim3(512), 512, 0, stream>>>(x, W1, b1, W2, b2, W3, b3, out);
}

// Round 23
// 26.756 us; speedup vs baseline: 4.8759x; 1.0132x over previous
//
#include <hip/hip_runtime.h>
#include <hip/hip_fp16.h>

typedef _Float16 half8  __attribute__((ext_vector_type(8)));
typedef _Float16 half4  __attribute__((ext_vector_type(4)));
typedef _Float16 h2v    __attribute__((ext_vector_type(2)));
typedef __fp16   fp16x2 __attribute__((ext_vector_type(2)));
typedef float    f32x4  __attribute__((ext_vector_type(4)));

#define B_N   2048
#define KLTOT 2048
#define LJ_   132         // rc stride per lj: 128 rc slots + 4 pad (lj*132%32 = lj*4 -> 2-way)
#define CSTR  (16 * LJ_)  // 2112 dwords per col
// xt[col][lj][rc]: row r <-> (lj = r&15, rc = r>>4)

// 5/5/4/4 h-slot packing
__device__ __forceinline__ int hmap(int g, int e) {
    return (g < 2) ? ((e < 5) ? g * 5 + e : -1)
                   : ((e < 4) ? 10 + (g - 2) * 4 + e : -1);
}

__device__ __forceinline__ unsigned int f16b(float f) {
    union { _Float16 h; unsigned short u; } c;
    c.h = (_Float16)f;
    return (unsigned int)c.u;
}

// Single kernel. Block = 4 FULL columns x 2048 batches (block-local stats).
// 512 blocks x 512 thr -> 2 blocks/CU, all co-resident.
// R23 = R22 with [col][lj][rc] LDS layout: Phase C does 4x ds_read_b128 prefetch
// (16 x-values ahead) + 4x ds_write_b128 per 16 iterations (LDS ops cut 4x,
// read latency covered 16-deep).
__global__ __launch_bounds__(512, 4) void fused_all(
    const float* __restrict__ x,
    const float* __restrict__ W1, const float* __restrict__ b1,
    const float* __restrict__ W2, const float* __restrict__ b2,
    const float* __restrict__ W3, const float* __restrict__ b3,
    float* __restrict__ out)
{
    __shared__ float        xt[4 * CSTR];        // 33.8 KB  [col][lj][rc]
    __shared__ unsigned int afb[1024];           // 4 KB     W2tmp (864 f32) then A-frags
    __shared__ float        wred[8][4][2];
    __shared__ unsigned int w1h[4][16], b1h[4][16], w3h[4][8];
    __shared__ float        b2f[4][16], smu[4], srs[4], sb3v[4];

    const int tid = threadIdx.x;
    const int bid = blockIdx.x;
    // XCD-chunked col swizzle: XCD k owns a contiguous 256-col band (2MB < 4MB L2)
    const int xk = bid & 7, jj = bid >> 3;
    const int cols0 = xk * 256 + (jj >> 3) * 32 + (jj & 7) * 4;

    const int w = tid >> 6, l = tid & 63;

    // ---- S1: single x pass: 16B row-slices -> LDS + in-register stats ----
    float s[4] = {0.f,0.f,0.f,0.f}, s2[4] = {0.f,0.f,0.f,0.f};
#pragma unroll
    for (int i = 0; i < 4; ++i) {
        int r = i * 512 + tid;
        f32x4 v = *(const f32x4*)(x + (size_t)r * KLTOT + cols0);
        int base = (r & 15) * LJ_ + (r >> 4);
#pragma unroll
        for (int e = 0; e < 4; ++e) {
            s[e] += v[e];
            s2[e] = fmaf(v[e], v[e], s2[e]);
            xt[e * CSTR + base] = v[e];
        }
    }
    {   // stage W2 (4 cols x 216 = 864 f32) into afb region
        float* W2tmp = (float*)afb;
        if (tid < 216)
            ((float4*)W2tmp)[tid] = ((const float4*)(W2 + (size_t)cols0 * 216))[tid];
    }
    // prefetch raw W1/b1 (folded after stats)
    float w1r0 = 0.f, w1r1 = 0.f, b1r0 = 0.f, b1r1 = 0.f;
    if (tid < 64) {
        int c2 = tid >> 4, ll = tid & 15, gg = ll >> 2, q = ll & 3;
        if (q < 3) {
            int h0 = hmap(gg, q * 2), h1_ = hmap(gg, q * 2 + 1);
            if (h0 >= 0) {
                w1r0 = W1[(size_t)(cols0 + c2) * 18 + h0];
                b1r0 = b1[(size_t)(cols0 + c2) * 18 + h0];
            }
            if (h1_ >= 0) {
                w1r1 = W1[(size_t)(cols0 + c2) * 18 + h1_];
                b1r1 = b1[(size_t)(cols0 + c2) * 18 + h1_];
            }
        }
    }
    // wave-level stats reduce
#pragma unroll
    for (int e = 0; e < 4; ++e) {
#pragma unroll
        for (int m = 1; m < 64; m <<= 1) {
            s[e]  += __shfl_xor(s[e],  m, 64);
            s2[e] += __shfl_xor(s2[e], m, 64);
        }
    }
    if (l == 0) {
#pragma unroll
        for (int e = 0; e < 4; ++e) { wred[w][e][0] = s[e]; wred[w][e][1] = s2[e]; }
    }
    __syncthreads();

    // ---- S2: stats final (t<4) || W2 frag-pack -> regs || mu-free tables ----
    if (tid < 4) {
        float S = 0.f, S2 = 0.f;
#pragma unroll
        for (int ww = 0; ww < 8; ++ww) { S += wred[ww][tid][0]; S2 += wred[ww][tid][1]; }
        float mu  = S / (float)B_N;
        float var = fmaxf(S2 / (float)B_N - mu * mu, 0.f);
        smu[tid]  = mu;
        srs[tid]  = 1.f / (sqrtf(var) + 1e-8f);
        sb3v[tid] = b3[cols0 + tid];
    }
    unsigned int dw[2];
    {
        const float* W2tmp = (const float*)afb;
#pragma unroll
        for (int i = 0; i < 2; ++i) {
            int idx = i * 512 + tid;
            int col = idx >> 8, d = idx & 255;
            unsigned int u[2];
#pragma unroll
            for (int h = 0; h < 2; ++h) {
                int id2 = d * 2 + h;
                int gg = id2 >> 7, jq = (id2 >> 3) & 15, e = id2 & 7;
                int hh = hmap(gg, e);
                float v = (hh >= 0 && jq < 12) ? W2tmp[col * 216 + hh * 12 + jq] : 0.f;
                u[h] = f16b(v);
            }
            dw[i] = u[0] | (u[1] << 16);
        }
    }
    if (tid >= 64 && tid < 128) {
        int t2 = tid - 64, c2 = t2 >> 4, ll = t2 & 15;
        b2f[c2][ll] = (ll < 12) ? b2[(size_t)(cols0 + c2) * 12 + ll] : 0.f;
    } else if (tid >= 128 && tid < 160) {
        int t2 = tid - 128, c2 = t2 >> 3, ll = t2 & 7;
        int j0 = 2 * ll, j1 = 2 * ll + 1;
        float v0 = (j0 < 12) ? W3[(size_t)(cols0 + c2) * 12 + j0] : 0.f;
        float v1 = (j1 < 12) ? W3[(size_t)(cols0 + c2) * 12 + j1] : 0.f;
        w3h[c2][ll] = f16b(v0) | (f16b(v1) << 16);
    }
    __syncthreads();

    // ---- S3: write A-frags || fold W1/b1 with stats ----
#pragma unroll
    for (int i = 0; i < 2; ++i)
        afb[i * 512 + tid] = dw[i];
    if (tid < 64) {
        int c2 = tid >> 4, ll = tid & 15, q = ll & 3;
        unsigned int wu = 0, bu = 0;
        if (q < 3) {
            float mu = smu[c2], rs = srs[c2];
            float w0 = w1r0 * rs, w1v = w1r1 * rs;
            float b0 = fmaf(-mu, w0, b1r0), b1v = fmaf(-mu, w1v, b1r1);
            wu = f16b(w0) | (f16b(w1v) << 16);
            bu = f16b(b0) | (f16b(b1v) << 16);
        }
        w1h[c2][ll] = wu;
        b1h[c2][ll] = bu;
    }
    __syncthreads();

    // ---- Phase C: dual chained MFMA; wave = 1 col x 1024 rows (64 iters) ----
    // 16-deep b128 prefetch per block of 16 iterations.
    const int g = l >> 4, lj = l & 15;
    const int cl = w & 3, rc0 = (w >> 2) * 64;

    union { uint4 u; half8 h; } af;
    af.u = *(const uint4*)&afb[cl * 256 + (g * 16 + lj) * 4];
    union { uint4 u; h2v p[4]; } w1u, b1u;
    w1u.u = *(const uint4*)&w1h[cl][g * 4];
    b1u.u = *(const uint4*)&b1h[cl][g * 4];
    union { uint2 u; half4 h; } a2;
    a2.u = *(const uint2*)&w3h[cl][g * 2];
    f32x4 b2r = *(const f32x4*)&b2f[cl][g * 4];
    const float b3v = sb3v[cl];
    const f32x4 bc3 = { b3v, b3v, b3v, b3v };     // b3 folded into MFMA2 C-operand
    const h2v z2 = {(_Float16)0.f, (_Float16)0.f};

    float* xbw = &xt[cl * CSTR + lj * LJ_ + rc0];
    union { h2v p[4]; half8 h; uint4 u; } bf;
    bf.u.w = 0u;                                   // zeroed once

#pragma unroll 1
    for (int blk = 0; blk < 4; ++blk) {
        float* xb = xbw + blk * 16;
        // 16-deep prefetch: 4x ds_read_b128 (lanes lj/lj+8 share banks -> 2-way, free)
        f32x4 xq0 = *(const f32x4*)(xb + 0);
        f32x4 xq1 = *(const f32x4*)(xb + 4);
        f32x4 xq2 = *(const f32x4*)(xb + 8);
        f32x4 xq3 = *(const f32x4*)(xb + 12);

        float res[16];
#pragma unroll
        for (int t = 0; t < 16; ++t) {
            float xsv = (t < 4) ? xq0[t & 3] : (t < 8) ? xq1[t & 3]
                      : (t < 12) ? xq2[t & 3] : xq3[t & 3];   // compile-time select
            _Float16 xh = (_Float16)xsv;
            h2v x2 = {xh, xh};
            bf.p[0] = __builtin_elementwise_max(x2 * w1u.p[0] + b1u.p[0], z2);
            bf.p[1] = __builtin_elementwise_max(x2 * w1u.p[1] + b1u.p[1], z2);
            bf.p[2] = __builtin_elementwise_max(x2 * w1u.p[2] + b1u.p[2], z2);

            // MFMA1: Z[j x b16] = W2^T * H1 + b2
            f32x4 acc = __builtin_amdgcn_mfma_f32_16x16x32_f16(af.h, bf.h, b2r, 0, 0, 0);

            union { fp16x2 c[2]; half4 h; } zf;
            zf.c[0] = __builtin_amdgcn_cvt_pkrtz(fmaxf(acc[0], 0.f), fmaxf(acc[1], 0.f));
            zf.c[1] = __builtin_amdgcn_cvt_pkrtz(fmaxf(acc[2], 0.f), fmaxf(acc[3], 0.f));

            // MFMA2: out[b] = W3^T * relu(Z) + b3  (C-in = b3 broadcast)
            f32x4 acc2 = __builtin_amdgcn_mfma_f32_16x16x16f16(a2.h, zf.h, bc3, 0, 0, 0);

            res[t] = acc2[0];                      // all 4 g-copies identical
        }
        // write back over consumed slots: 4x ds_write_b128 (same-value 4-way dup)
        f32x4 r0 = { res[0],  res[1],  res[2],  res[3]  };
        f32x4 r1 = { res[4],  res[5],  res[6],  res[7]  };
        f32x4 r2 = { res[8],  res[9],  res[10], res[11] };
        f32x4 r3 = { res[12], res[13], res[14], res[15] };
        *(f32x4*)(xb + 0)  = r0;
        *(f32x4*)(xb + 4)  = r1;
        *(f32x4*)(xb + 8)  = r2;
        *(f32x4*)(xb + 12) = r3;
    }
    __syncthreads();

    // ---- store: out[r][cols0..cols0+3] = 16B row-slices (L2-merged) ----
#pragma unroll
    for (int i = 0; i < 4; ++i) {
        int r = i * 512 + tid;
        int base = (r & 15) * LJ_ + (r >> 4);
        f32x4 v = { xt[0 * CSTR + base], xt[1 * CSTR + base],
                    xt[2 * CSTR + base], xt[3 * CSTR + base] };
        *(f32x4*)(out + (size_t)r * KLTOT + cols0) = v;
    }
}

extern "C" void kernel_launch(void* const* d_in, const int* in_sizes, int n_in,
                              void* d_out, int out_size, void* d_ws, size_t ws_size,
                              hipStream_t stream) {
    const float* x  = (const float*)d_in[0];
    const float* W1 = (const float*)d_in[1];
    const float* b1 = (const float*)d_in[2];
    const float* W2 = (const float*)d_in[3];
    const float* b2 = (const float*)d_in[4];
    const float* W3 = (const float*)d_in[5];
    const float* b3 = (const float*)d_in[6];
    float* out = (float*)d_out;

    fused_all<<<dim3(512), 512, 0, stream>>>(x, W1, b1, W2, b2, W3, b3, out);
}